// Round 1
// baseline (1175.013 us; speedup 1.0000x reference)
//
#include <hip/hip_runtime.h>
#include <math.h>

#define NATOM 4096
#define NM    1024
#define NKR   9260      // real k-vectors (21^3 - 1)
#define KSPLIT 14
#define CHPS  22        // chunks per split
#define NCH   308       // KSPLIT*CHPS
#define KC    32
#define KPAD2 9856      // NCH*KC
#define PI_F  3.14159265358979f

typedef short v8s __attribute__((ext_vector_type(8)));   // 8 bf16 (4 VGPRs)
typedef float v4f __attribute__((ext_vector_type(4)));   // 4 fp32

// ---------- k-vector data computed inline (device helper) ----------
static __device__ __forceinline__ void kdata(int t, const float* __restrict__ cell,
                                             float& kxx, float& kyy, float& kzz, float& w) {
  if (t >= NKR) { kxx = 0.f; kyy = 0.f; kzz = 0.f; w = 0.f; return; }
  int u = (t < 4630) ? t : t + 1;       // skip the all-zero triple
  int a = u / 441;
  int rem = u - a * 441;
  int b = rem / 21;
  int c = rem - b * 21;
  float na = (float)(a - 10), nb = (float)(b - 10), nc = (float)(c - 10);
  float m00=cell[0], m01=cell[1], m02=cell[2];
  float m10=cell[3], m11=cell[4], m12=cell[5];
  float m20=cell[6], m21=cell[7], m22=cell[8];
  float det = m00*(m11*m22 - m12*m21) - m01*(m10*m22 - m12*m20) + m02*(m10*m21 - m11*m20);
  float inv00 =  (m11*m22 - m12*m21) / det;
  float inv01 = -(m01*m22 - m02*m21) / det;
  float inv02 =  (m01*m12 - m02*m11) / det;
  float inv10 = -(m10*m22 - m12*m20) / det;
  float inv11 =  (m00*m22 - m02*m20) / det;
  float inv12 = -(m00*m12 - m02*m10) / det;
  float inv20 =  (m10*m21 - m11*m20) / det;
  float inv21 = -(m00*m21 - m01*m20) / det;
  float inv22 =  (m00*m11 - m01*m10) / det;
  const float twopi = 2.f * PI_F;
  kxx = twopi * (na*inv00 + nb*inv01 + nc*inv02);
  kyy = twopi * (na*inv10 + nb*inv11 + nc*inv12);
  kzz = twopi * (na*inv20 + nb*inv21 + nc*inv22);
  float k2 = kxx*kxx + kyy*kyy + kzz*kzz;
  const float sigma = 1.0f / 1.805132f;
  w = (4.f * PI_F / fabsf(det)) * __expf(-0.5f * sigma * sigma * k2) / k2;
}

// ---------- sfk: k-data + structure factors in one kernel.
__global__ __launch_bounds__(256)
void sfk(const float* __restrict__ pos, const float* __restrict__ q,
         const float* __restrict__ cell,
         float* __restrict__ kx, float* __restrict__ ky,
         float* __restrict__ kz, float* __restrict__ ksw,
         float* __restrict__ gc, float* __restrict__ gs) {
  __shared__ float red1[8][32], red2[8][32];
  const int kloc = threadIdx.x & 31;
  const int part = threadIdx.x >> 5;             // 0..7
  const int k = blockIdx.x * 32 + kloc;          // < KPAD2
  float kxx, kyy, kzz, w;
  kdata(k, cell, kxx, kyy, kzz, w);
  if (part == 0) { kx[k]=kxx; ky[k]=kyy; kz[k]=kzz; ksw[k]=sqrtf(w); }
  float sc = 0.f, ss = 0.f;
  const int j0 = NM + part * 384, j1 = j0 + 384;
  for (int j = j0; j < j1; ++j) {
    float kr = kxx*pos[3*j] + kyy*pos[3*j+1] + kzz*pos[3*j+2];
    float s, c;
    __sincosf(kr, &s, &c);
    float qj = q[j];
    sc += qj * c;
    ss += qj * s;
  }
  red1[part][kloc] = sc;
  red2[part][kloc] = ss;
  __syncthreads();
  if (part == 0) {
    float tc = 0.f, ts = 0.f;
    #pragma unroll
    for (int pp = 0; pp < 8; ++pp) { tc += red1[pp][kloc]; ts += red2[pp][kloc]; }
    gc[k] = w * tc;
    gs[k] = w * ts;
  }
}

// ----------------- B = -f at metal positions; also init r2 = ones
__global__ __launch_bounds__(256)
void fB(const float* __restrict__ pos,
        const float* __restrict__ kx, const float* __restrict__ ky,
        const float* __restrict__ kz,
        const float* __restrict__ gc, const float* __restrict__ gs,
        float* __restrict__ r1, float* __restrict__ r2) {
  int i = blockIdx.x;
  float px = pos[3*i], py = pos[3*i+1], pz = pos[3*i+2];
  float p = 0.f;
  for (int k = threadIdx.x; k < KPAD2; k += 256) {
    float kr = kx[k]*px + ky[k]*py + kz[k]*pz;
    float s, c;
    __sincosf(kr, &s, &c);
    p += gc[k]*c + gs[k]*s;
  }
  for (int o = 32; o > 0; o >>= 1) p += __shfl_down(p, o, 64);
  __shared__ float red[4];
  if ((threadIdx.x & 63) == 0) red[threadIdx.x >> 6] = p;
  __syncthreads();
  if (threadIdx.x == 0) {
    r1[i] = -(red[0] + red[1] + red[2] + red[3]);
    r2[i] = 1.f;
  }
}

// --------------- A = C W C^T + S W S^T, upper 128-tiles only (bi<=bj)
// MFMA 3-pass split-bf16 with XOR-swizzled k-group slots (R15 verbatim).
#define PSTR 40
__global__ __launch_bounds__(256, 2)
void gemmA(const float* __restrict__ pos,
           const float* __restrict__ kx, const float* __restrict__ ky,
           const float* __restrict__ kz, const float* __restrict__ ksw,
           float* __restrict__ A) {
  __shared__ short Pl[8][128 * PSTR];
  const int blk = blockIdx.x;
  const int split = blk / 36;
  const int tt = blk - split * 36;
  int bi = 0, rem = tt;
  while (rem >= 8 - bi) { rem -= 8 - bi; ++bi; }
  const int bj = bi + rem;
  const int t = threadIdx.x;
  const int side = t >> 7;
  const int a = t & 127;
  const int atom = (side ? bj : bi) * 128 + a;
  const float px = pos[3*atom], py = pos[3*atom+1], pz = pos[3*atom+2];
  const int axor = (a >> 3) & 3;
  short* PC_hi = &Pl[side*4+0][a*PSTR];
  short* PC_mi = &Pl[side*4+1][a*PSTR];
  short* PS_hi = &Pl[side*4+2][a*PSTR];
  short* PS_mi = &Pl[side*4+3][a*PSTR];

  const int w = t >> 6;          // wave id 0..3 -> rows [w*32, w*32+32)
  const int lane = t & 63;
  const int ln15 = lane & 15;
  const int quad = lane >> 4;

  v4f acc[2][8];
  #pragma unroll
  for (int mt = 0; mt < 2; ++mt)
    #pragma unroll
    for (int nt = 0; nt < 8; ++nt) {
      v4f z = {0.f, 0.f, 0.f, 0.f};
      acc[mt][nt] = z;
    }

  for (int ch = split * CHPS; ch < split * CHPS + CHPS; ++ch) {
    const int kb = ch * KC;
    #pragma unroll
    for (int g = 0; g < 4; ++g) {
      v8s vch, vcm, vsh, vsm;
      #pragma unroll
      for (int j = 0; j < 8; ++j) {
        const int gk = kb + g*8 + j;
        float kr = kx[gk]*px + ky[gk]*py + kz[gk]*pz;
        float s, c;
        __sincosf(kr, &s, &c);
        float sw = ksw[gk];
        float cv = c * sw, sv = s * sw;
        unsigned cu = __float_as_uint(cv);
        float chf = __uint_as_float(cu & 0xffff0000u);
        unsigned cmu = __float_as_uint(cv - chf);
        unsigned su = __float_as_uint(sv);
        float shf = __uint_as_float(su & 0xffff0000u);
        unsigned smu = __float_as_uint(sv - shf);
        vch[j] = (short)(cu >> 16);
        vcm[j] = (short)(cmu >> 16);
        vsh[j] = (short)(su >> 16);
        vsm[j] = (short)(smu >> 16);
      }
      const int slot = (g ^ axor) * 8;
      *(v8s*)&PC_hi[slot] = vch;
      *(v8s*)&PC_mi[slot] = vcm;
      *(v8s*)&PS_hi[slot] = vsh;
      *(v8s*)&PS_mi[slot] = vsm;
    }
    __syncthreads();
    v8s aCh[2], aCm[2], aSh[2], aSm[2];
    #pragma unroll
    for (int mt = 0; mt < 2; ++mt) {
      const int row = w*32 + mt*16 + ln15;
      const int off = row * PSTR + (quad ^ ((row >> 3) & 3)) * 8;
      aCh[mt] = *(const v8s*)&Pl[0][off];
      aCm[mt] = *(const v8s*)&Pl[1][off];
      aSh[mt] = *(const v8s*)&Pl[2][off];
      aSm[mt] = *(const v8s*)&Pl[3][off];
    }
    #pragma unroll
    for (int nt = 0; nt < 8; ++nt) {
      const int row = nt*16 + ln15;
      const int off = row * PSTR + (quad ^ ((row >> 3) & 3)) * 8;
      v8s bCh = *(const v8s*)&Pl[4][off];
      v8s bCm = *(const v8s*)&Pl[5][off];
      v8s bSh = *(const v8s*)&Pl[6][off];
      v8s bSm = *(const v8s*)&Pl[7][off];
      #pragma unroll
      for (int mt = 0; mt < 2; ++mt) {
        v4f d = acc[mt][nt];
        d = __builtin_amdgcn_mfma_f32_16x16x32_bf16(aCh[mt], bCh, d, 0, 0, 0);
        d = __builtin_amdgcn_mfma_f32_16x16x32_bf16(aCh[mt], bCm, d, 0, 0, 0);
        d = __builtin_amdgcn_mfma_f32_16x16x32_bf16(aCm[mt], bCh, d, 0, 0, 0);
        d = __builtin_amdgcn_mfma_f32_16x16x32_bf16(aSh[mt], bSh, d, 0, 0, 0);
        d = __builtin_amdgcn_mfma_f32_16x16x32_bf16(aSh[mt], bSm, d, 0, 0, 0);
        d = __builtin_amdgcn_mfma_f32_16x16x32_bf16(aSm[mt], bSh, d, 0, 0, 0);
        acc[mt][nt] = d;
      }
    }
    __syncthreads();
  }
  #pragma unroll
  for (int mt = 0; mt < 2; ++mt)
    #pragma unroll
    for (int nt = 0; nt < 8; ++nt)
      #pragma unroll
      for (int r = 0; r < 4; ++r) {
        const int row = bi*128 + w*32 + mt*16 + quad*4 + r;
        const int col = bj*128 + nt*16 + ln15;
        atomicAdd(&A[row*1024 + col], acc[mt][nt][r]);
      }
}

// ---------- in-wave 32x32 Cholesky of Dl[r0..r0+31][c0..c0+31], lanes t<32 = rows
static __device__ __forceinline__ void chol32(float (*Dl)[65], int r0, int c0, int t) {
  float a[32];
  #pragma unroll
  for (int m = 0; m < 32; ++m) a[m] = Dl[r0 + t][c0 + m];
  #pragma unroll
  for (int j = 0; j < 32; ++j) {
    float dj = __shfl(a[j], j);
    float rinv = rsqrtf(dj);
    float lj = (t == j) ? dj * rinv : a[j] * rinv;
    a[j] = lj;
    #pragma unroll
    for (int m = j + 1; m < 32; ++m)
      a[m] -= lj * __shfl(lj, m);
  }
  #pragma unroll
  for (int m = 0; m < 32; ++m) Dl[r0 + t][c0 + m] = a[m];  // upper garbage, never read
}

// ---------- per-row blocked TRSM: solve row * L^T = row, L lower in Lm
static __device__ __forceinline__ void trsm_row(float* row, const float (*Lm)[65], int ncb) {
  for (int cb = 0; cb < ncb; ++cb) {
    const int cbase = cb * 16;
    float x[16];
    #pragma unroll
    for (int k = 0; k < 16; ++k) x[k] = row[cbase + k];
    for (int m = 0; m < cbase; ++m) {
      float tm = row[m];                        // own solved value
      #pragma unroll
      for (int k = 0; k < 16; ++k)
        x[k] -= tm * Lm[cbase + k][m];          // broadcast L read
    }
    #pragma unroll
    for (int k = 0; k < 16; ++k) {
      float xv = x[k] * (1.0f / Lm[cbase + k][cbase + k]);
      x[k] = xv;
      #pragma unroll
      for (int m2 = k + 1; m2 < 16; ++m2)
        x[m2] -= xv * Lm[cbase + m2][cbase + k];
    }
    #pragma unroll
    for (int k = 0; k < 16; ++k) row[cbase + k] = x[k];
  }
}

// ============ step(p): 64-wide panels (16 launches), fused lazy-syrk + panel ============
// A storage: gemmA wrote full diagonal 128-blocks + upper off-diag 128-blocks;
// lower off-diag 128-blocks are 0 until the factor L overwrites them (64-granular).
// Launch p: syrk blocks apply panel p-1 to trailing tiles (qi,qj >= p+1);
// panel blocks apply panel p-1 in-register, factor diag hierarchically (2x chol32),
// TRSM their tile against the full 64-factor, and fuse the forward solve.
__global__ __launch_bounds__(256)
void step(float* __restrict__ A, const float* __restrict__ r1, const float* __restrict__ r2,
          float* __restrict__ ru1, float* __restrict__ ru2,
          float* __restrict__ y1g, float* __restrict__ y2g, int p) {
  __shared__ float D[64][65];
  __shared__ float T[64][65];
  __shared__ float y1s[64], y2s[64];
  const int t = threadIdx.x;
  const int nb = 16 - p;
  const int i0 = (t >> 4) * 4, j0 = (t & 15) * 4;   // 4x4 micro-tile

  if ((int)blockIdx.x >= nb) {
    // ---------------- syrk role (only launched for p >= 1) ----------------
    int rem = blockIdx.x - nb, aa = 0;
    while (rem >= aa + 1) { rem -= (aa + 1); ++aa; }
    const int qi = p + 1 + aa, qj = p + 1 + rem;    // qi >= qj >= p+1
    for (int e = t; e < 4096; e += 256) {
      int r = e >> 6, c = e & 63;
      D[r][c] = A[(qi*64 + r)*1024 + (p-1)*64 + c];  // L(qi,p-1)
      T[r][c] = A[(qj*64 + r)*1024 + (p-1)*64 + c];  // L(qj,p-1)
    }
    float o[4][4];
    if (p == 1 && (qi >> 1) != (qj >> 1)) {
      #pragma unroll
      for (int ii = 0; ii < 4; ++ii)
        #pragma unroll
        for (int jj = 0; jj < 4; ++jj)
          o[ii][jj] = A[(qj*64 + j0+jj)*1024 + qi*64 + i0+ii];   // orig from upper
    } else {
      #pragma unroll
      for (int ii = 0; ii < 4; ++ii)
        #pragma unroll
        for (int jj = 0; jj < 4; ++jj)
          o[ii][jj] = A[(qi*64 + i0+ii)*1024 + qj*64 + j0+jj];
    }
    __syncthreads();
    for (int m = 0; m < 64; ++m) {
      float a0 = D[i0][m], a1 = D[i0+1][m], a2 = D[i0+2][m], a3 = D[i0+3][m];
      float b0 = T[j0][m], b1 = T[j0+1][m], b2 = T[j0+2][m], b3 = T[j0+3][m];
      o[0][0]-=a0*b0; o[0][1]-=a0*b1; o[0][2]-=a0*b2; o[0][3]-=a0*b3;
      o[1][0]-=a1*b0; o[1][1]-=a1*b1; o[1][2]-=a1*b2; o[1][3]-=a1*b3;
      o[2][0]-=a2*b0; o[2][1]-=a2*b1; o[2][2]-=a2*b2; o[2][3]-=a2*b3;
      o[3][0]-=a3*b0; o[3][1]-=a3*b1; o[3][2]-=a3*b2; o[3][3]-=a3*b3;
    }
    #pragma unroll
    for (int ii = 0; ii < 4; ++ii)
      #pragma unroll
      for (int jj = 0; jj < 4; ++jj)
        A[(qi*64 + i0+ii)*1024 + qj*64 + j0+jj] = o[ii][jj];
    return;
  }

  // ---------------- panel role: tile (q, p) ----------------
  const int b = blockIdx.x;
  const int q = p + b;
  if (p == 0) {
    for (int e = t; e < 4096; e += 256) {
      int r = e >> 6, c = e & 63;
      D[r][c] = A[r*1024 + c];                                   // A(0,0)
    }
    if (b > 0) {
      if (q == 1) {
        for (int e = t; e < 4096; e += 256) {
          int r = e >> 6, c = e & 63;
          T[r][c] = A[(64 + r)*1024 + c];                        // direct (diag 128-blk)
        }
      } else {
        for (int e = t; e < 4096; e += 256) {
          int r = e >> 6, c = e & 63;
          T[c][r] = A[r*1024 + q*64 + c];                        // A(0,q)^T
        }
      }
    }
    __syncthreads();
  } else {
    for (int e = t; e < 4096; e += 256) {
      int r = e >> 6, c = e & 63;
      D[r][c] = A[(p*64 + r)*1024 + (p-1)*64 + c];               // L(p,p-1)
      if (b > 0)
        T[r][c] = A[(q*64 + r)*1024 + (p-1)*64 + c];             // L(q,p-1)
    }
    __syncthreads();
    // diag update o1 = A(p,p) - L(p,p-1) L(p,p-1)^T
    float o1[4][4];
    #pragma unroll
    for (int ii = 0; ii < 4; ++ii)
      #pragma unroll
      for (int jj = 0; jj < 4; ++jj)
        o1[ii][jj] = A[(p*64+i0+ii)*1024 + p*64 + j0+jj];
    for (int m = 0; m < 64; ++m) {
      float a0 = D[i0][m], a1 = D[i0+1][m], a2 = D[i0+2][m], a3 = D[i0+3][m];
      float b0 = D[j0][m], b1 = D[j0+1][m], b2 = D[j0+2][m], b3 = D[j0+3][m];
      o1[0][0]-=a0*b0; o1[0][1]-=a0*b1; o1[0][2]-=a0*b2; o1[0][3]-=a0*b3;
      o1[1][0]-=a1*b0; o1[1][1]-=a1*b1; o1[1][2]-=a1*b2; o1[1][3]-=a1*b3;
      o1[2][0]-=a2*b0; o1[2][1]-=a2*b1; o1[2][2]-=a2*b2; o1[2][3]-=a2*b3;
      o1[3][0]-=a3*b0; o1[3][1]-=a3*b1; o1[3][2]-=a3*b2; o1[3][3]-=a3*b3;
    }
    float o2[4][4];
    if (b > 0) {
      // own-tile update o2 = A(q,p) - L(q,p-1) L(p,p-1)^T
      if (p == 1) {        // q >= 2 crosses the 128-block: orig lives in upper
        #pragma unroll
        for (int ii = 0; ii < 4; ++ii)
          #pragma unroll
          for (int jj = 0; jj < 4; ++jj)
            o2[ii][jj] = A[(64 + j0+jj)*1024 + q*64 + i0+ii];
      } else {
        #pragma unroll
        for (int ii = 0; ii < 4; ++ii)
          #pragma unroll
          for (int jj = 0; jj < 4; ++jj)
            o2[ii][jj] = A[(q*64+i0+ii)*1024 + p*64 + j0+jj];
      }
      for (int m = 0; m < 64; ++m) {
        float a0 = T[i0][m], a1 = T[i0+1][m], a2 = T[i0+2][m], a3 = T[i0+3][m];
        float b0 = D[j0][m], b1 = D[j0+1][m], b2 = D[j0+2][m], b3 = D[j0+3][m];
        o2[0][0]-=a0*b0; o2[0][1]-=a0*b1; o2[0][2]-=a0*b2; o2[0][3]-=a0*b3;
        o2[1][0]-=a1*b0; o2[1][1]-=a1*b1; o2[1][2]-=a1*b2; o2[1][3]-=a1*b3;
        o2[2][0]-=a2*b0; o2[2][1]-=a2*b1; o2[2][2]-=a2*b2; o2[2][3]-=a2*b3;
        o2[3][0]-=a3*b0; o2[3][1]-=a3*b1; o2[3][2]-=a3*b2; o2[3][3]-=a3*b3;
      }
    }
    __syncthreads();   // done reading D,T as L-tiles
    #pragma unroll
    for (int ii = 0; ii < 4; ++ii)
      #pragma unroll
      for (int jj = 0; jj < 4; ++jj)
        D[i0+ii][j0+jj] = o1[ii][jj];
    if (b > 0) {
      #pragma unroll
      for (int ii = 0; ii < 4; ++ii)
        #pragma unroll
        for (int jj = 0; jj < 4; ++jj)
          T[i0+ii][j0+jj] = o2[ii][jj];
    }
    __syncthreads();
  }

  // ---- hierarchical 64x64 Cholesky of D ----
  if (t < 32) chol32(D, 0, 0, t);                 // L00
  __syncthreads();
  if (t < 32) trsm_row(&D[32 + t][0], D, 2);      // L10 = D10 L00^-T
  __syncthreads();
  {
    // D11 -= L10 L10^T   (all 256 threads, 2x2 micro on the 32x32 block)
    const int si = 32 + (t >> 4) * 2, sj = 32 + (t & 15) * 2;
    float s00 = 0.f, s01 = 0.f, s10 = 0.f, s11 = 0.f;
    #pragma unroll
    for (int m = 0; m < 32; ++m) {
      float a0 = D[si][m], a1 = D[si+1][m];
      float b0 = D[sj][m], b1 = D[sj+1][m];
      s00 += a0*b0; s01 += a0*b1; s10 += a1*b0; s11 += a1*b1;
    }
    D[si][sj]   -= s00; D[si][sj+1]   -= s01;
    D[si+1][sj] -= s10; D[si+1][sj+1] -= s11;
  }
  __syncthreads();
  if (t < 32) chol32(D, 32, 32, t);               // L11
  __syncthreads();

  // ---- full-wave TRSM of own tile: solve T L^T = T ----
  if (b > 0 && t < 64) trsm_row(&T[t][0], D, 4);
  __syncthreads();

  // ---- stores ----
  if (b == 0) {
    for (int e = t; e < 4096; e += 256) {
      int r = e >> 6, c = e & 63;
      if (r >= c) A[(p*64 + r)*1024 + p*64 + c] = D[r][c];
    }
  } else {
    for (int e = t; e < 4096; e += 256) {
      int r = e >> 6, c = e & 63;
      A[(q*64 + r)*1024 + p*64 + c] = T[r][c];
    }
  }

  // ---- forward solve y_p = L_pp^{-1} r_p (redundant per block, full wave) ----
  if (t < 64) {
    float v1 = r1[p*64 + t], v2 = r2[p*64 + t];
    for (int j = 0; j < 64; ++j) {
      float invd = 1.f / D[j][j];
      float Lij = D[t][j];
      float x1 = __shfl(v1, j) * invd;
      float x2 = __shfl(v2, j) * invd;
      if (t == j)      { v1 = x1; v2 = x2; }
      else if (t > j)  { v1 -= Lij * x1; v2 -= Lij * x2; }
    }
    y1s[t] = v1; y2s[t] = v2;
    if (b == 0) { y1g[p*64 + t] = v1; y2g[p*64 + t] = v2; }
  }
  __syncthreads();
  if (b > 0 && t < 64) {
    float a1 = 0.f, a2 = 0.f;
    for (int j = 0; j < 64; ++j) {
      float lv = T[t][j];
      a1 += lv * y1s[j];
      a2 += lv * y2s[j];
    }
    ru1[q*64 + t] -= a1;
    ru2[q*64 + t] -= a2;
  }
}

// ------- invd: invert the 16 diagonal 64x64 L blocks in parallel.
// Block k, 64 threads; thread j computes column j of X = L^{-1} (lower).
// Upper parts of the stored diag tiles are garbage -> masked to 0 on load.
__global__ __launch_bounds__(64)
void invd(const float* __restrict__ A, float* __restrict__ iD) {
  __shared__ float Lb[64][65];
  __shared__ float Xs[64][65];
  const int k = blockIdx.x;
  const int j = threadIdx.x;
  const int base = k * 64;
  for (int e = j; e < 4096; e += 64) {
    int r = e >> 6, c = e & 63;
    Lb[r][c] = (r >= c) ? A[(base + r)*1024 + base + c] : 0.f;
  }
  __syncthreads();
  // column j: X[r][j], r from j to 63 (thread-private column, no races)
  for (int r = 0; r < j; ++r) Xs[r][j] = 0.f;
  Xs[j][j] = 1.f / Lb[j][j];
  for (int r = j + 1; r < 64; ++r) {
    float s = 0.f;
    for (int m = j; m < r; ++m) s += Lb[r][m] * Xs[m][j];
    Xs[r][j] = -s / Lb[r][r];
  }
  __syncthreads();
  for (int e = j; e < 4096; e += 64)
    iD[k*4096 + e] = Xs[e>>6][e&63];
}

// --------- backward solve via precomputed invL blocks: per panel p,
// x_p = invL_p^T y_p (GEMV, no dependent chain), then trailing update.
__global__ __launch_bounds__(1024)
void bwd_out(const float* __restrict__ A, const float* __restrict__ iD,
             float* __restrict__ y1g, float* __restrict__ y2g,
             const float* __restrict__ qin, float* __restrict__ out) {
  __shared__ float D[64][65];
  __shared__ float yin1[64], yin2[64];
  __shared__ float x1s[64], x2s[64];
  __shared__ float rs1[16], rs2[16];
  const int t = threadIdx.x;
  for (int p = 15; p >= 0; --p) {
    const int base = p * 64;
    for (int e = t; e < 4096; e += 1024)
      D[e>>6][e&63] = iD[p*4096 + e];
    if (t < 64) { yin1[t] = y1g[base + t]; yin2[t] = y2g[base + t]; }
    __syncthreads();
    if (t < 64) {
      // x[t] = sum_m invL[m][t] * y[m]  (invL stored full, zeros above diag)
      float v1 = 0.f, v2 = 0.f;
      #pragma unroll 8
      for (int m = 0; m < 64; ++m) {
        float w = D[m][t];
        v1 += w * yin1[m];
        v2 += w * yin2[m];
      }
      y1g[base + t] = v1; y2g[base + t] = v2;
      x1s[t] = v1; x2s[t] = v2;
    }
    __syncthreads();
    for (int rr = t; rr < base; rr += 1024) {
      float a1 = 0.f, a2 = 0.f;
      #pragma unroll 8
      for (int jj = 0; jj < 64; ++jj) {
        float lv = A[(base+jj)*1024 + rr];
        a1 += lv * x1s[jj];
        a2 += lv * x2s[jj];
      }
      y1g[rr] -= a1; y2g[rr] -= a2;
    }
    __syncthreads();
  }
  float s1 = y1g[t], s2 = y2g[t];
  for (int o = 32; o > 0; o >>= 1) { s1 += __shfl_down(s1, o, 64); s2 += __shfl_down(s2, o, 64); }
  if ((t & 63) == 0) { rs1[t >> 6] = s1; rs2[t >> 6] = s2; }
  __syncthreads();
  if (t == 0) {
    float a = 0.f, bb = 0.f;
    #pragma unroll
    for (int w = 0; w < 16; ++w) { a += rs1[w]; bb += rs2[w]; }
    rs1[0] = a / bb;
  }
  __syncthreads();
  const float lam = rs1[0];
  out[t] = y1g[t] - lam * y2g[t];
  for (int e = NM + t; e < NATOM; e += 1024) out[e] = qin[e];
}

// --------------------------------------------------------------- launch
extern "C" void kernel_launch(void* const* d_in, const int* in_sizes, int n_in,
                              void* d_out, int out_size, void* d_ws, size_t ws_size,
                              hipStream_t stream) {
  const float* pos  = (const float*)d_in[0];
  const float* q    = (const float*)d_in[1];
  const float* cell = (const float*)d_in[2];
  float* out = (float*)d_out;

  float* ws  = (float*)d_ws;
  float* A   = ws;                                   // 1,048,576 floats
  float* kx  = ws + 1048576;
  float* ky  = kx + KPAD2;
  float* kz  = ky + KPAD2;
  float* ksw = kz + KPAD2;
  float* gc  = ksw + KPAD2;                          // KPAD2
  float* gs  = gc + KPAD2;                           // KPAD2
  float* r1  = gs + KPAD2;                           // 1024
  float* r2  = r1 + 1024;                            // 1024
  float* y1g = r2 + 1024;                            // 1024
  float* y2g = y1g + 1024;                           // 1024
  float* iD  = y2g + 1024;                           // 16 * 4096

  sfk<<<NCH, 256, 0, stream>>>(pos, q, cell, kx, ky, kz, ksw, gc, gs);
  fB<<<NM, 256, 0, stream>>>(pos, kx, ky, kz, gc, gs, r1, r2);
  hipMemsetAsync(A, 0, 1024 * 1024 * sizeof(float), stream);
  gemmA<<<36 * KSPLIT, 256, 0, stream>>>(pos, kx, ky, kz, ksw, A);
  for (int p = 0; p < 16; ++p) {
    const int s = 15 - p;
    const int grid = (16 - p) + ((p >= 1) ? s * (s + 1) / 2 : 0);
    step<<<grid, 256, 0, stream>>>(A, r1, r2, r1, r2, y1g, y2g, p);
  }
  invd<<<16, 64, 0, stream>>>(A, iD);
  bwd_out<<<1, 1024, 0, stream>>>(A, iD, y1g, y2g, q, out);
}

// Round 2
// 786.332 us; speedup vs baseline: 1.4943x; 1.4943x over previous
//
#include <hip/hip_runtime.h>
#include <math.h>

#define NATOM 4096
#define NM    1024
#define NKR   9260      // real k-vectors (21^3 - 1)
#define KSPLIT 14
#define CHPS  22        // chunks per split
#define NCH   308       // KSPLIT*CHPS
#define KC    32
#define KPAD2 9856      // NCH*KC
#define PI_F  3.14159265358979f

typedef short v8s __attribute__((ext_vector_type(8)));   // 8 bf16 (4 VGPRs)
typedef float v4f __attribute__((ext_vector_type(4)));   // 4 fp32

// ---------- k-vector data computed inline (device helper) ----------
static __device__ __forceinline__ void kdata(int t, const float* __restrict__ cell,
                                             float& kxx, float& kyy, float& kzz, float& w) {
  if (t >= NKR) { kxx = 0.f; kyy = 0.f; kzz = 0.f; w = 0.f; return; }
  int u = (t < 4630) ? t : t + 1;       // skip the all-zero triple
  int a = u / 441;
  int rem = u - a * 441;
  int b = rem / 21;
  int c = rem - b * 21;
  float na = (float)(a - 10), nb = (float)(b - 10), nc = (float)(c - 10);
  float m00=cell[0], m01=cell[1], m02=cell[2];
  float m10=cell[3], m11=cell[4], m12=cell[5];
  float m20=cell[6], m21=cell[7], m22=cell[8];
  float det = m00*(m11*m22 - m12*m21) - m01*(m10*m22 - m12*m20) + m02*(m10*m21 - m11*m20);
  float inv00 =  (m11*m22 - m12*m21) / det;
  float inv01 = -(m01*m22 - m02*m21) / det;
  float inv02 =  (m01*m12 - m02*m11) / det;
  float inv10 = -(m10*m22 - m12*m20) / det;
  float inv11 =  (m00*m22 - m02*m20) / det;
  float inv12 = -(m00*m12 - m02*m10) / det;
  float inv20 =  (m10*m21 - m11*m20) / det;
  float inv21 = -(m00*m21 - m01*m20) / det;
  float inv22 =  (m00*m11 - m01*m10) / det;
  const float twopi = 2.f * PI_F;
  kxx = twopi * (na*inv00 + nb*inv01 + nc*inv02);
  kyy = twopi * (na*inv10 + nb*inv11 + nc*inv12);
  kzz = twopi * (na*inv20 + nb*inv21 + nc*inv22);
  float k2 = kxx*kxx + kyy*kyy + kzz*kzz;
  const float sigma = 1.0f / 1.805132f;
  w = (4.f * PI_F / fabsf(det)) * __expf(-0.5f * sigma * sigma * k2) / k2;
}

// ---------- sfk: k-data + structure factors in one kernel.
__global__ __launch_bounds__(256)
void sfk(const float* __restrict__ pos, const float* __restrict__ q,
         const float* __restrict__ cell,
         float* __restrict__ kx, float* __restrict__ ky,
         float* __restrict__ kz, float* __restrict__ ksw,
         float* __restrict__ gc, float* __restrict__ gs) {
  __shared__ float red1[8][32], red2[8][32];
  const int kloc = threadIdx.x & 31;
  const int part = threadIdx.x >> 5;             // 0..7
  const int k = blockIdx.x * 32 + kloc;          // < KPAD2
  float kxx, kyy, kzz, w;
  kdata(k, cell, kxx, kyy, kzz, w);
  if (part == 0) { kx[k]=kxx; ky[k]=kyy; kz[k]=kzz; ksw[k]=sqrtf(w); }
  float sc = 0.f, ss = 0.f;
  const int j0 = NM + part * 384, j1 = j0 + 384;
  for (int j = j0; j < j1; ++j) {
    float kr = kxx*pos[3*j] + kyy*pos[3*j+1] + kzz*pos[3*j+2];
    float s, c;
    __sincosf(kr, &s, &c);
    float qj = q[j];
    sc += qj * c;
    ss += qj * s;
  }
  red1[part][kloc] = sc;
  red2[part][kloc] = ss;
  __syncthreads();
  if (part == 0) {
    float tc = 0.f, ts = 0.f;
    #pragma unroll
    for (int pp = 0; pp < 8; ++pp) { tc += red1[pp][kloc]; ts += red2[pp][kloc]; }
    gc[k] = w * tc;
    gs[k] = w * ts;
  }
}

// ----------------- B = -f at metal positions; also init r2 = ones
__global__ __launch_bounds__(256)
void fB(const float* __restrict__ pos,
        const float* __restrict__ kx, const float* __restrict__ ky,
        const float* __restrict__ kz,
        const float* __restrict__ gc, const float* __restrict__ gs,
        float* __restrict__ r1, float* __restrict__ r2) {
  int i = blockIdx.x;
  float px = pos[3*i], py = pos[3*i+1], pz = pos[3*i+2];
  float p = 0.f;
  for (int k = threadIdx.x; k < KPAD2; k += 256) {
    float kr = kx[k]*px + ky[k]*py + kz[k]*pz;
    float s, c;
    __sincosf(kr, &s, &c);
    p += gc[k]*c + gs[k]*s;
  }
  for (int o = 32; o > 0; o >>= 1) p += __shfl_down(p, o, 64);
  __shared__ float red[4];
  if ((threadIdx.x & 63) == 0) red[threadIdx.x >> 6] = p;
  __syncthreads();
  if (threadIdx.x == 0) {
    r1[i] = -(red[0] + red[1] + red[2] + red[3]);
    r2[i] = 1.f;
  }
}

// --------------- A = C W C^T + S W S^T, upper 128-tiles only (bi<=bj)
// MFMA 3-pass split-bf16 with XOR-swizzled k-group slots (R15 verbatim).
#define PSTR 40
__global__ __launch_bounds__(256, 2)
void gemmA(const float* __restrict__ pos,
           const float* __restrict__ kx, const float* __restrict__ ky,
           const float* __restrict__ kz, const float* __restrict__ ksw,
           float* __restrict__ A) {
  __shared__ short Pl[8][128 * PSTR];
  const int blk = blockIdx.x;
  const int split = blk / 36;
  const int tt = blk - split * 36;
  int bi = 0, rem = tt;
  while (rem >= 8 - bi) { rem -= 8 - bi; ++bi; }
  const int bj = bi + rem;
  const int t = threadIdx.x;
  const int side = t >> 7;
  const int a = t & 127;
  const int atom = (side ? bj : bi) * 128 + a;
  const float px = pos[3*atom], py = pos[3*atom+1], pz = pos[3*atom+2];
  const int axor = (a >> 3) & 3;
  short* PC_hi = &Pl[side*4+0][a*PSTR];
  short* PC_mi = &Pl[side*4+1][a*PSTR];
  short* PS_hi = &Pl[side*4+2][a*PSTR];
  short* PS_mi = &Pl[side*4+3][a*PSTR];

  const int w = t >> 6;          // wave id 0..3 -> rows [w*32, w*32+32)
  const int lane = t & 63;
  const int ln15 = lane & 15;
  const int quad = lane >> 4;

  v4f acc[2][8];
  #pragma unroll
  for (int mt = 0; mt < 2; ++mt)
    #pragma unroll
    for (int nt = 0; nt < 8; ++nt) {
      v4f z = {0.f, 0.f, 0.f, 0.f};
      acc[mt][nt] = z;
    }

  for (int ch = split * CHPS; ch < split * CHPS + CHPS; ++ch) {
    const int kb = ch * KC;
    #pragma unroll
    for (int g = 0; g < 4; ++g) {
      v8s vch, vcm, vsh, vsm;
      #pragma unroll
      for (int j = 0; j < 8; ++j) {
        const int gk = kb + g*8 + j;
        float kr = kx[gk]*px + ky[gk]*py + kz[gk]*pz;
        float s, c;
        __sincosf(kr, &s, &c);
        float sw = ksw[gk];
        float cv = c * sw, sv = s * sw;
        unsigned cu = __float_as_uint(cv);
        float chf = __uint_as_float(cu & 0xffff0000u);
        unsigned cmu = __float_as_uint(cv - chf);
        unsigned su = __float_as_uint(sv);
        float shf = __uint_as_float(su & 0xffff0000u);
        unsigned smu = __float_as_uint(sv - shf);
        vch[j] = (short)(cu >> 16);
        vcm[j] = (short)(cmu >> 16);
        vsh[j] = (short)(su >> 16);
        vsm[j] = (short)(smu >> 16);
      }
      const int slot = (g ^ axor) * 8;
      *(v8s*)&PC_hi[slot] = vch;
      *(v8s*)&PC_mi[slot] = vcm;
      *(v8s*)&PS_hi[slot] = vsh;
      *(v8s*)&PS_mi[slot] = vsm;
    }
    __syncthreads();
    v8s aCh[2], aCm[2], aSh[2], aSm[2];
    #pragma unroll
    for (int mt = 0; mt < 2; ++mt) {
      const int row = w*32 + mt*16 + ln15;
      const int off = row * PSTR + (quad ^ ((row >> 3) & 3)) * 8;
      aCh[mt] = *(const v8s*)&Pl[0][off];
      aCm[mt] = *(const v8s*)&Pl[1][off];
      aSh[mt] = *(const v8s*)&Pl[2][off];
      aSm[mt] = *(const v8s*)&Pl[3][off];
    }
    #pragma unroll
    for (int nt = 0; nt < 8; ++nt) {
      const int row = nt*16 + ln15;
      const int off = row * PSTR + (quad ^ ((row >> 3) & 3)) * 8;
      v8s bCh = *(const v8s*)&Pl[4][off];
      v8s bCm = *(const v8s*)&Pl[5][off];
      v8s bSh = *(const v8s*)&Pl[6][off];
      v8s bSm = *(const v8s*)&Pl[7][off];
      #pragma unroll
      for (int mt = 0; mt < 2; ++mt) {
        v4f d = acc[mt][nt];
        d = __builtin_amdgcn_mfma_f32_16x16x32_bf16(aCh[mt], bCh, d, 0, 0, 0);
        d = __builtin_amdgcn_mfma_f32_16x16x32_bf16(aCh[mt], bCm, d, 0, 0, 0);
        d = __builtin_amdgcn_mfma_f32_16x16x32_bf16(aCm[mt], bCh, d, 0, 0, 0);
        d = __builtin_amdgcn_mfma_f32_16x16x32_bf16(aSh[mt], bSh, d, 0, 0, 0);
        d = __builtin_amdgcn_mfma_f32_16x16x32_bf16(aSh[mt], bSm, d, 0, 0, 0);
        d = __builtin_amdgcn_mfma_f32_16x16x32_bf16(aSm[mt], bSh, d, 0, 0, 0);
        acc[mt][nt] = d;
      }
    }
    __syncthreads();
  }
  #pragma unroll
  for (int mt = 0; mt < 2; ++mt)
    #pragma unroll
    for (int nt = 0; nt < 8; ++nt)
      #pragma unroll
      for (int r = 0; r < 4; ++r) {
        const int row = bi*128 + w*32 + mt*16 + quad*4 + r;
        const int col = bj*128 + nt*16 + ln15;
        atomicAdd(&A[row*1024 + col], acc[mt][nt][r]);
      }
}

// ============ step(p): b=32 panels, fused lazy-syrk + panel ============
// Deferred-y variant: at launch p, each panel block applies y_{p-1} (from y1g/y2g,
// computed by launch p-1's b=0 block) to its r-rows using the already-loaded
// correction tile (D for b=0 in-register, T for b>0 via global RMW). Only b=0
// runs the serial forward-solve chain; b>0 blocks skip it entirely.
__global__ __launch_bounds__(256)
void step(float* __restrict__ A, const float* __restrict__ r1, const float* __restrict__ r2,
          float* __restrict__ ru1, float* __restrict__ ru2,
          float* __restrict__ y1g, float* __restrict__ y2g, int p) {
  __shared__ __align__(16) float D[32][36];
  __shared__ __align__(16) float T[32][36];
  __shared__ float yp1[32], yp2[32];
  const int t = threadIdx.x;
  const int nb = 32 - p;
  const int i0 = (t >> 4) * 2, j0 = (t & 15) * 2;   // 2x2 micro-tile
  const int lr = t >> 3, lc = (t & 7) * 4;          // float4 tile coords

  if ((int)blockIdx.x >= nb) {
    // ---------------- syrk role (only launched for p >= 1) ----------------
    int rem = blockIdx.x - nb, a = 0;
    while (rem >= a + 1) { rem -= (a + 1); ++a; }
    const int qi = p + 1 + a, qj = p + 1 + rem;     // qi >= qj >= p+1
    *(v4f*)&D[lr][lc] = *(const v4f*)&A[(qi*32+lr)*1024 + (p-1)*32 + lc];  // L(qi,p-1)
    *(v4f*)&T[lr][lc] = *(const v4f*)&A[(qj*32+lr)*1024 + (p-1)*32 + lc];  // L(qj,p-1)
    float o[2][2];
    if (p == 1 && (qi >> 2) != (qj >> 2)) {
      #pragma unroll
      for (int ii = 0; ii < 2; ++ii)
        #pragma unroll
        for (int jj = 0; jj < 2; ++jj)
          o[ii][jj] = A[(qj*32 + j0+jj)*1024 + qi*32 + i0+ii];
    } else {
      #pragma unroll
      for (int ii = 0; ii < 2; ++ii)
        #pragma unroll
        for (int jj = 0; jj < 2; ++jj)
          o[ii][jj] = A[(qi*32+i0+ii)*1024 + qj*32 + j0+jj];
    }
    __syncthreads();
    for (int m = 0; m < 32; ++m) {
      float a0 = D[i0][m], a1 = D[i0+1][m];
      float b0 = T[j0][m], b1 = T[j0+1][m];
      o[0][0]-=a0*b0; o[0][1]-=a0*b1;
      o[1][0]-=a1*b0; o[1][1]-=a1*b1;
    }
    #pragma unroll
    for (int ii = 0; ii < 2; ++ii)
      #pragma unroll
      for (int jj = 0; jj < 2; ++jj)
        A[(qi*32+i0+ii)*1024 + qj*32 + j0+jj] = o[ii][jj];
    return;
  }

  // ---------------- panel role: tile (q, p) ----------------
  const int b = blockIdx.x;
  const int q = p + b;
  float rv1 = 0.f, rv2 = 0.f;    // b==0, t<32: corrected r for the fwd chain
  if (p >= 1 && t < 32) { yp1[t] = y1g[(p-1)*32 + t]; yp2[t] = y2g[(p-1)*32 + t]; }
  if (p == 0) {
    *(v4f*)&D[lr][lc] = *(const v4f*)&A[lr*1024 + lc];                    // A(0,0)
    if (b > 0) {
      if (q < 4) {
        *(v4f*)&T[lr][lc] = *(const v4f*)&A[(q*32+lr)*1024 + lc];         // direct
      } else {
        for (int e = t; e < 1024; e += 256)
          T[e&31][e>>5] = A[(e>>5)*1024 + q*32 + (e&31)];                 // A(0,q)^T
      }
    }
    __syncthreads();
    if (b == 0 && t < 32) { rv1 = r1[t]; rv2 = r2[t]; }
  } else {
    *(v4f*)&D[lr][lc] = *(const v4f*)&A[(p*32+lr)*1024 + (p-1)*32 + lc];  // L(p,p-1)
    if (b > 0)
      *(v4f*)&T[lr][lc] = *(const v4f*)&A[(q*32+lr)*1024 + (p-1)*32 + lc];// L(q,p-1)
    __syncthreads();
    // ---- deferred y_{p-1} application (reuses the correction tiles) ----
    if (t < 32) {
      if (b == 0) {
        float a1 = 0.f, a2 = 0.f;
        for (int j = 0; j < 32; ++j) {
          float lv = D[t][j];
          a1 += lv * yp1[j];
          a2 += lv * yp2[j];
        }
        rv1 = r1[p*32 + t] - a1;
        rv2 = r2[p*32 + t] - a2;
      } else {
        float a1 = 0.f, a2 = 0.f;
        for (int j = 0; j < 32; ++j) {
          float lv = T[t][j];
          a1 += lv * yp1[j];
          a2 += lv * yp2[j];
        }
        ru1[q*32 + t] -= a1;
        ru2[q*32 + t] -= a2;
      }
    }
    // diag update o1 = A(p,p) - L(p,p-1) L(p,p-1)^T
    float o1[2][2];
    #pragma unroll
    for (int ii = 0; ii < 2; ++ii)
      #pragma unroll
      for (int jj = 0; jj < 2; ++jj)
        o1[ii][jj] = A[(p*32+i0+ii)*1024 + p*32 + j0+jj];
    for (int m = 0; m < 32; ++m) {
      float a0 = D[i0][m], a1 = D[i0+1][m];
      float b0 = D[j0][m], b1 = D[j0+1][m];
      o1[0][0]-=a0*b0; o1[0][1]-=a0*b1;
      o1[1][0]-=a1*b0; o1[1][1]-=a1*b1;
    }
    float o2[2][2];
    if (b > 0) {
      // own-tile update o2 = A(q,p) - L(q,p-1) L(p,p-1)^T
      if (p == 1 && (q >> 2) != 0) {
        #pragma unroll
        for (int ii = 0; ii < 2; ++ii)
          #pragma unroll
          for (int jj = 0; jj < 2; ++jj)
            o2[ii][jj] = A[(1*32 + j0+jj)*1024 + q*32 + i0+ii];
      } else {
        #pragma unroll
        for (int ii = 0; ii < 2; ++ii)
          #pragma unroll
          for (int jj = 0; jj < 2; ++jj)
            o2[ii][jj] = A[(q*32+i0+ii)*1024 + p*32 + j0+jj];
      }
      for (int m = 0; m < 32; ++m) {
        float a0 = T[i0][m], a1 = T[i0+1][m];
        float b0 = D[j0][m], b1 = D[j0+1][m];
        o2[0][0]-=a0*b0; o2[0][1]-=a0*b1;
        o2[1][0]-=a1*b0; o2[1][1]-=a1*b1;
      }
    }
    __syncthreads();   // done reading D,T as L-tiles
    #pragma unroll
    for (int ii = 0; ii < 2; ++ii)
      #pragma unroll
      for (int jj = 0; jj < 2; ++jj)
        D[i0+ii][j0+jj] = o1[ii][jj];
    if (b > 0) {
      #pragma unroll
      for (int ii = 0; ii < 2; ++ii)
        #pragma unroll
        for (int jj = 0; jj < 2; ++jj)
          T[i0+ii][j0+jj] = o2[ii][jj];
    }
    __syncthreads();
  }

  // ---- wave-register Cholesky of D (lanes 0..31; lane = row) ----
  if (t < 32) {
    float a[32];
    #pragma unroll
    for (int m = 0; m < 32; ++m) a[m] = D[t][m];
    #pragma unroll
    for (int j = 0; j < 32; ++j) {
      float dj = __shfl(a[j], j);
      float rinv = rsqrtf(dj);
      float lj = (t == j) ? dj * rinv : a[j] * rinv;
      a[j] = lj;
      #pragma unroll
      for (int m = j + 1; m < 32; ++m)
        a[m] -= lj * __shfl(lj, m);
    }
    #pragma unroll
    for (int m = 0; m < 32; ++m) D[t][m] = a[m];  // upper garbage, never read
  }
  __syncthreads();
  if (b == 0) {
    for (int e = t; e < 1024; e += 256) {
      int i = e >> 5, j = e & 31;
      if (i >= j) A[(p*32+i)*1024 + p*32 + j] = D[i][j];
    }
    // forward solve y_p = L_pp^{-1} r_p (only here; b>0 blocks skip the chain)
    if (t < 32) {
      float v1 = rv1, v2 = rv2;
      for (int j = 0; j < 32; ++j) {
        float invd = 1.f / D[j][j];
        float Lij = D[t][j];
        float x1 = __shfl(v1, j) * invd;
        float x2 = __shfl(v2, j) * invd;
        if (t == j)      { v1 = x1; v2 = x2; }
        else if (t > j)  { v1 -= Lij * x1; v2 -= Lij * x2; }
      }
      y1g[p*32 + t] = v1; y2g[p*32 + t] = v2;
    }
  } else {
    // ---- blocked-register TRSM: solve X L^T = T (lanes 0..31 = rows) ----
    if (t < 32) {
      #pragma unroll
      for (int cb = 0; cb < 2; ++cb) {
        const int cbase = cb * 16;
        float x[16];
        #pragma unroll
        for (int k = 0; k < 16; ++k) x[k] = T[t][cbase + k];
        for (int m = 0; m < cbase; ++m) {
          float tm = T[t][m];                       // own solved value
          #pragma unroll
          for (int k = 0; k < 16; ++k)
            x[k] -= tm * D[cbase + k][m];           // broadcast L read
        }
        #pragma unroll
        for (int k = 0; k < 16; ++k) {
          float xv = x[k] * (1.0f / D[cbase + k][cbase + k]);
          x[k] = xv;
          #pragma unroll
          for (int m2 = k + 1; m2 < 16; ++m2)
            x[m2] -= xv * D[cbase + m2][cbase + k];
        }
        #pragma unroll
        for (int k = 0; k < 16; ++k) T[t][cbase + k] = x[k];
      }
    }
    __syncthreads();
    *(v4f*)&A[(q*32+lr)*1024 + p*32 + lc] = *(const v4f*)&T[lr][lc];
  }
}

// ------- invd: invert the 16 diagonal 64x64 L blocks in parallel.
// Block k, 64 threads; thread j computes column j of X = L^{-1} (lower).
// Upper parts of the stored diag tiles are garbage -> masked to 0 on load.
__global__ __launch_bounds__(64)
void invd(const float* __restrict__ A, float* __restrict__ iD) {
  __shared__ float Lb[64][65];
  __shared__ float Xs[64][65];
  const int k = blockIdx.x;
  const int j = threadIdx.x;
  const int base = k * 64;
  for (int e = j; e < 4096; e += 64) {
    int r = e >> 6, c = e & 63;
    Lb[r][c] = (r >= c) ? A[(base + r)*1024 + base + c] : 0.f;
  }
  __syncthreads();
  // column j: X[r][j], r from j to 63 (thread-private column, no races)
  for (int r = 0; r < j; ++r) Xs[r][j] = 0.f;
  Xs[j][j] = 1.f / Lb[j][j];
  for (int r = j + 1; r < 64; ++r) {
    float s = 0.f;
    for (int m = j; m < r; ++m) s += Lb[r][m] * Xs[m][j];
    Xs[r][j] = -s / Lb[r][r];
  }
  __syncthreads();
  for (int e = j; e < 4096; e += 64)
    iD[k*4096 + e] = Xs[e>>6][e&63];
}

// --------- backward solve via precomputed invL blocks: per panel p,
// x_p = invL_p^T y_p (GEMV, no dependent chain), then trailing update.
__global__ __launch_bounds__(1024)
void bwd_out(const float* __restrict__ A, const float* __restrict__ iD,
             float* __restrict__ y1g, float* __restrict__ y2g,
             const float* __restrict__ qin, float* __restrict__ out) {
  __shared__ float D[64][65];
  __shared__ float yin1[64], yin2[64];
  __shared__ float x1s[64], x2s[64];
  __shared__ float rs1[16], rs2[16];
  const int t = threadIdx.x;
  for (int p = 15; p >= 0; --p) {
    const int base = p * 64;
    for (int e = t; e < 4096; e += 1024)
      D[e>>6][e&63] = iD[p*4096 + e];
    if (t < 64) { yin1[t] = y1g[base + t]; yin2[t] = y2g[base + t]; }
    __syncthreads();
    if (t < 64) {
      // x[t] = sum_m invL[m][t] * y[m]  (invL stored full, zeros above diag)
      float v1 = 0.f, v2 = 0.f;
      #pragma unroll 8
      for (int m = 0; m < 64; ++m) {
        float w = D[m][t];
        v1 += w * yin1[m];
        v2 += w * yin2[m];
      }
      y1g[base + t] = v1; y2g[base + t] = v2;
      x1s[t] = v1; x2s[t] = v2;
    }
    __syncthreads();
    for (int rr = t; rr < base; rr += 1024) {
      float a1 = 0.f, a2 = 0.f;
      #pragma unroll 8
      for (int jj = 0; jj < 64; ++jj) {
        float lv = A[(base+jj)*1024 + rr];
        a1 += lv * x1s[jj];
        a2 += lv * x2s[jj];
      }
      y1g[rr] -= a1; y2g[rr] -= a2;
    }
    __syncthreads();
  }
  float s1 = y1g[t], s2 = y2g[t];
  for (int o = 32; o > 0; o >>= 1) { s1 += __shfl_down(s1, o, 64); s2 += __shfl_down(s2, o, 64); }
  if ((t & 63) == 0) { rs1[t >> 6] = s1; rs2[t >> 6] = s2; }
  __syncthreads();
  if (t == 0) {
    float a = 0.f, bb = 0.f;
    #pragma unroll
    for (int w = 0; w < 16; ++w) { a += rs1[w]; bb += rs2[w]; }
    rs1[0] = a / bb;
  }
  __syncthreads();
  const float lam = rs1[0];
  out[t] = y1g[t] - lam * y2g[t];
  for (int e = NM + t; e < NATOM; e += 1024) out[e] = qin[e];
}

// --------------------------------------------------------------- launch
extern "C" void kernel_launch(void* const* d_in, const int* in_sizes, int n_in,
                              void* d_out, int out_size, void* d_ws, size_t ws_size,
                              hipStream_t stream) {
  const float* pos  = (const float*)d_in[0];
  const float* q    = (const float*)d_in[1];
  const float* cell = (const float*)d_in[2];
  float* out = (float*)d_out;

  float* ws  = (float*)d_ws;
  float* A   = ws;                                   // 1,048,576 floats
  float* kx  = ws + 1048576;
  float* ky  = kx + KPAD2;
  float* kz  = ky + KPAD2;
  float* ksw = kz + KPAD2;
  float* gc  = ksw + KPAD2;                          // KPAD2
  float* gs  = gc + KPAD2;                           // KPAD2
  float* r1  = gs + KPAD2;                           // 1024
  float* r2  = r1 + 1024;                            // 1024
  float* y1g = r2 + 1024;                            // 1024
  float* y2g = y1g + 1024;                           // 1024
  float* iD  = y2g + 1024;                           // 16 * 4096

  sfk<<<NCH, 256, 0, stream>>>(pos, q, cell, kx, ky, kz, ksw, gc, gs);
  fB<<<NM, 256, 0, stream>>>(pos, kx, ky, kz, gc, gs, r1, r2);
  hipMemsetAsync(A, 0, 1024 * 1024 * sizeof(float), stream);
  gemmA<<<36 * KSPLIT, 256, 0, stream>>>(pos, kx, ky, kz, ksw, A);
  for (int p = 0; p < 32; ++p) {
    const int s = 31 - p;
    const int grid = (32 - p) + ((p >= 1) ? s * (s + 1) / 2 : 0);
    step<<<grid, 256, 0, stream>>>(A, r1, r2, r1, r2, y1g, y2g, p);
  }
  invd<<<16, 64, 0, stream>>>(A, iD);
  bwd_out<<<1, 1024, 0, stream>>>(A, iD, y1g, y2g, q, out);
}